// Round 1
// baseline (61.170 us; speedup 1.0000x reference)
//
#include <hip/hip_runtime.h>
#include <math.h>

// Problem constants (match reference)
#define B_ 32
#define T_ 8192
#define C_ 64
#define S_ 32            // t-chunks per batch row
#define L_ (T_ / S_)     // 256 t per chunk
#define EPS_ 1e-8f
#define SIGMA_MIN_ 1e-4f

// Workspace layout (float offsets)
#define SUM_OFF 0                       // B_*S_*C_ = 65536
#define SQ_OFF  65536                   // 65536
#define MS_OFF  131072                  // 65536
#define GAP_OFF 196608                  // B_*S_*4 ints = 4096 (as ints)
#define MU_OFF  200704                  // B_*C_ = 2048
#define INV_OFF 202752                  // 2048
// total = 204800 floats = 800 KiB

// ---------------- Kernel 1: per-(b,chunk) partial stats + gap tuple ----------
__global__ __launch_bounds__(256) void k1_stats(const float* __restrict__ x,
                                                const float* __restrict__ mask,
                                                float* __restrict__ ws) {
    const int bid = blockIdx.x;            // 0 .. B_*S_-1
    const int b   = bid / S_;
    const int s   = bid % S_;
    const int tid = threadIdx.x;
    const int cq  = tid & 15;              // channel quad 0..15 (c = cq*4..cq*4+3)
    const int tg  = tid >> 4;              // t-group 0..15

    const float4* x4 = (const float4*)x;
    const float4* m4 = (const float4*)mask;
    // float4 index of (b, t, cq*4): (b*T_ + t)*16 + cq
    const long base = (long)(b * T_ + s * L_) * 16 + cq;

    float4 s1 = make_float4(0.f, 0.f, 0.f, 0.f);
    float4 s2 = make_float4(0.f, 0.f, 0.f, 0.f);
    float4 sm = make_float4(0.f, 0.f, 0.f, 0.f);

#pragma unroll
    for (int it = 0; it < L_ / 16; ++it) {
        long idx = base + (long)(it * 16 + tg) * 16;
        float4 xv = x4[idx];
        float4 mv = m4[idx];
        s1.x += xv.x; s1.y += xv.y; s1.z += xv.z; s1.w += xv.w;
        s2.x += xv.x * xv.x; s2.y += xv.y * xv.y;
        s2.z += xv.z * xv.z; s2.w += xv.w * xv.w;
        sm.x += mv.x; sm.y += mv.y; sm.z += mv.z; sm.w += mv.w;
    }

    __shared__ float4 shA[256];
    __shared__ float4 shB[256];
    __shared__ float4 shC[256];
    shA[tid] = s1; shB[tid] = s2; shC[tid] = sm;
    __syncthreads();

    // reduce over t-groups (stride multiples of 16 keep cq fixed)
    for (int off = 128; off >= 16; off >>= 1) {
        if (tid < off) {
            float4 a = shA[tid], b2 = shA[tid + off];
            a.x += b2.x; a.y += b2.y; a.z += b2.z; a.w += b2.w; shA[tid] = a;
            float4 c = shB[tid], d = shB[tid + off];
            c.x += d.x; c.y += d.y; c.z += d.z; c.w += d.w; shB[tid] = c;
            float4 e = shC[tid], f = shC[tid + off];
            e.x += f.x; e.y += f.y; e.z += f.z; e.w += f.w; shC[tid] = e;
        }
        __syncthreads();
    }

    if (tid < 16) {
        const int o = bid * C_ + tid * 4;   // (b*S_+s)*C_ + c
        ((float4*)(ws + SUM_OFF))[o >> 2] = shA[tid];
        ((float4*)(ws + SQ_OFF ))[o >> 2] = shB[tid];
        ((float4*)(ws + MS_OFF ))[o >> 2] = shC[tid];
    }

    // ---- gap tuple for this chunk (mask channel 0, L_=256 t values) ----
    const int t = s * L_ + tid;                       // tid 0..255 covers chunk
    const float m0 = mask[((long)b * T_ + t) * C_];   // channel 0
    const bool miss = (m0 < 0.5f);
    unsigned long long w = __ballot(miss);            // bit lane = t order

    __shared__ unsigned long long words[4];
    if ((tid & 63) == 0) words[tid >> 6] = w;
    __syncthreads();

    if (tid == 0) {
        int pre = 0, suf = 0, best = 0, len = 0;
        for (int i = 0; i < 4; ++i) {
            unsigned long long wi = words[i];
            int p_i, s_i, b_i;
            if (wi == ~0ull) {
                p_i = 64; s_i = 64; b_i = 64;
            } else {
                p_i = __builtin_ctzll(~wi);   // leading (low-bit) run of 1s
                s_i = __builtin_clzll(~wi);   // trailing (high-bit) run of 1s
                unsigned long long tmp = wi; b_i = 0;
                while (tmp) { tmp &= (tmp << 1); ++b_i; }
            }
            if (i == 0) { pre = p_i; suf = s_i; best = b_i; len = 64; }
            else {
                int cross = suf + p_i;
                best = max(best, max(b_i, cross));
                pre  = (pre == len) ? len + p_i : pre;
                suf  = (s_i == 64) ? suf + 64 : s_i;
                len += 64;
            }
        }
        int* gp = (int*)(ws + GAP_OFF) + bid * 4;
        gp[0] = pre; gp[1] = suf; gp[2] = best;
    }
}

// ---------------- Kernel 2: combine partials -> per-(b,c) mu, 1/sigma --------
__global__ __launch_bounds__(64) void k2_params(const int*   __restrict__ phase_id,
                                                const float* __restrict__ anchor_mu,
                                                const float* __restrict__ anchor_ls,
                                                const float* __restrict__ tau0_raw,
                                                const float* __restrict__ tau1_raw,
                                                float* __restrict__ ws) {
    const int b = blockIdx.x;
    const int c = threadIdx.x;

    __shared__ float sh_gap;
    if (c == 0) {
        const int* gp = (const int*)(ws + GAP_OFF);
        int pre = 0, suf = 0, best = 0, len = 0;
        for (int s = 0; s < S_; ++s) {
            const int* g = gp + (b * S_ + s) * 4;
            int p_i = g[0], s_i = g[1], b_i = g[2];
            if (s == 0) { pre = p_i; suf = s_i; best = b_i; len = L_; }
            else {
                int cross = suf + p_i;
                best = max(best, max(b_i, cross));
                pre  = (pre == len) ? len + p_i : pre;
                suf  = (s_i == L_) ? suf + L_ : s_i;
                len += L_;
            }
        }
        sh_gap = (float)best / (float)T_;
    }
    __syncthreads();

    float sum = 0.f, sq = 0.f, ms = 0.f;
    for (int s = 0; s < S_; ++s) {
        int o = (b * S_ + s) * C_ + c;
        sum += ws[SUM_OFF + o];
        sq  += ws[SQ_OFF  + o];
        ms  += ws[MS_OFF  + o];
    }

    const float msc    = fmaxf(ms, EPS_);
    const float mu_obs = sum / msc;
    // var = (Σ m x² − 2 μ Σ m x + μ² Σ m) / msc   (matches reference expansion)
    float var = (sq - 2.f * mu_obs * sum + mu_obs * mu_obs * ms) / msc;
    var = fmaxf(var, 0.f);
    const float sigma_obs = sqrtf(var + EPS_);
    const float coverage  = ms / (float)T_;

    const float t0 = log1pf(expf(tau0_raw[0]));   // softplus
    const float t1 = log1pf(expf(tau1_raw[0]));
    const float w  = coverage / (coverage + t0 + t1 * sh_gap + EPS_);

    const int   pid    = phase_id[b];
    const float mu_ref = anchor_mu[pid * C_ + c];
    const float ls_ref = anchor_ls[pid * C_ + c];

    const float mu = w * mu_obs + (1.f - w) * mu_ref;
    const float ls = w * logf(sigma_obs + EPS_) + (1.f - w) * ls_ref;
    const float sigma = fmaxf(expf(ls), SIGMA_MIN_);

    ws[MU_OFF  + b * C_ + c] = mu;
    ws[INV_OFF + b * C_ + c] = 1.f / sigma;
}

// ---------------- Kernel 3: elementwise normalize ---------------------------
__global__ __launch_bounds__(256) void k3_norm(const float* __restrict__ x,
                                               const float* __restrict__ mask,
                                               const float* __restrict__ token,
                                               const float* __restrict__ ws,
                                               float* __restrict__ out) {
    const int gid = blockIdx.x * 256 + threadIdx.x;   // float4 index
    const float4* x4 = (const float4*)x;
    const float4* m4 = (const float4*)mask;
    const float4* mu4  = (const float4*)(ws + MU_OFF);
    const float4* inv4 = (const float4*)(ws + INV_OFF);
    const float4* tk4  = (const float4*)token;

    const int b = gid >> 17;            // T_*C_/4 = 131072 float4 per b
    const int p = b * 16 + (gid & 15);  // (b, channel-quad)

    float4 xv = x4[gid];
    float4 mv = m4[gid];
    float4 mu = mu4[p];
    float4 iv = inv4[p];
    float4 tk = tk4[gid & 15];

    float4 o;
    o.x = mv.x * ((xv.x - mu.x) * iv.x) + (1.f - mv.x) * tk.x;
    o.y = mv.y * ((xv.y - mu.y) * iv.y) + (1.f - mv.y) * tk.y;
    o.z = mv.z * ((xv.z - mu.z) * iv.z) + (1.f - mv.z) * tk.z;
    o.w = mv.w * ((xv.w - mu.w) * iv.w) + (1.f - mv.w) * tk.w;

    ((float4*)out)[gid] = o;
}

extern "C" void kernel_launch(void* const* d_in, const int* in_sizes, int n_in,
                              void* d_out, int out_size, void* d_ws, size_t ws_size,
                              hipStream_t stream) {
    const float* x    = (const float*)d_in[0];
    const float* mask = (const float*)d_in[1];
    const int*   pid  = (const int*)  d_in[2];
    const float* amu  = (const float*)d_in[3];
    const float* als  = (const float*)d_in[4];
    const float* t0   = (const float*)d_in[5];
    const float* t1   = (const float*)d_in[6];
    const float* tok  = (const float*)d_in[7];
    float* out = (float*)d_out;
    float* ws  = (float*)d_ws;

    k1_stats<<<B_ * S_, 256, 0, stream>>>(x, mask, ws);
    k2_params<<<B_, 64, 0, stream>>>(pid, amu, als, t0, t1, ws);
    const int n4 = B_ * T_ * C_ / 4;          // 4194304 float4s
    k3_norm<<<n4 / 256, 256, 0, stream>>>(x, mask, tok, ws, out);
}